// Round 3
// baseline (240.293 us; speedup 1.0000x reference)
//
#include <hip/hip_runtime.h>
#include <math.h>

// Problem constants (fixed by setup_inputs): B=512, C=3000, T=25.
#define B_ 512
#define C_ 3000
#define T_ 25
#define C4_ (C_ / 4)            // 750 float4 per row

typedef float v4f __attribute__((ext_vector_type(4)));

// R8: async-DMA read path test. Headline = ~180 us harness fills (fixed) +
// ace_rows. R6 ace_rows ~45 us = 3.7 TB/s read; R7's 4x occupancy made it
// WORSE -> not latency-bound. Fills prove DRAM does 6.8 TB/s one-way; copy
// ubench read component is ~3.15 TB/s -> suspect per-CU cap on VGPR-dest
// load tracking. global_load_lds (async global->LDS DMA, no VGPR writeback)
// is the one untried read path. Per-wave private LDS slices -> NO barriers;
// depth-2 double buffer with counted s_waitcnt vmcnt(3) (never 0 mid-loop).
#define GLOAD_LDS16(g, l)                                                     \
  __builtin_amdgcn_global_load_lds(                                           \
      (const __attribute__((address_space(1))) unsigned int*)(g),             \
      (__attribute__((address_space(3))) unsigned int*)(l), 16, 0, 0)

__global__ __launch_bounds__(256, 2) void ace_rows(
    const float* __restrict__ logit_var,   // [B,1]
    const float* __restrict__ pred,        // [B,C]
    const float* __restrict__ tru,         // [B,C]
    const float* __restrict__ noise,       // [T,B,C]
    float* __restrict__ dsum)              // [T+1] per-t sum over b of row loss
{
    const int tid  = threadIdx.x;
    const int b    = blockIdx.x;
    const int wave = tid >> 6;

    // 2 x 750 float4 = 24 KB noise double-buffer. Wave w owns slice
    // [k*256 + w*64 .. +64) of each 256-f4 chunk k -> no cross-wave sharing.
    __shared__ float4 nbuf[2][C4_];

    const float4* __restrict__ p4 = (const float4*)(pred + (size_t)b * C_);
    const float4* __restrict__ t4 = (const float4*)(tru  + (size_t)b * C_);

    const int  i0   = tid;
    const int  i1   = tid + 256;
    const bool has2 = (tid < C4_ - 512);        // tid < 238
    const int  i2   = has2 ? tid + 512 : tid;   // clamped (safe) address

    const float stdv = sqrtf(logit_var[b]);

    float4 pv0 = p4[i0], pv1 = p4[i1], pv2 = p4[i2];
    float4 tv0 = t4[i0], tv1 = t4[i1], tv2 = t4[i2];

    float p[12], tr[12];
    p[0]=pv0.x; p[1]=pv0.y; p[2]=pv0.z; p[3]=pv0.w;
    p[4]=pv1.x; p[5]=pv1.y; p[6]=pv1.z; p[7]=pv1.w;
    p[8]=pv2.x; p[9]=pv2.y; p[10]=pv2.z; p[11]=pv2.w;
    tr[0]=tv0.x; tr[1]=tv0.y; tr[2]=tv0.z; tr[3]=tv0.w;
    tr[4]=tv1.x; tr[5]=tv1.y; tr[6]=tv1.z; tr[7]=tv1.w;
    tr[8]=tv2.x; tr[9]=tv2.y; tr[10]=tv2.z; tr[11]=tv2.w;
    if (!has2) {
        // poison tail lanes: exp(-1e30)=0, tr=0 kills dot/Tm contributions.
#pragma unroll
        for (int j = 8; j < 12; ++j) { p[j] = -1e30f; tr[j] = 0.f; }
    }

    float S[T_ + 1], D[T_ + 1];
    float Tm = 0.f;
    // undistorted row (index T_): x = pred
    {
        float s_acc = 0.f, d_acc = 0.f;
#pragma unroll
        for (int j = 0; j < 12; ++j) {
            s_acc += __expf(p[j]);
            d_acc  = fmaf(p[j], tr[j], d_acc);
            Tm    += tr[j];
        }
        S[T_] = s_acc; D[T_] = d_acc;
    }

    // Drain pred/true loads so the vmcnt immediates below count ONLY the
    // noise DMA loads.
    asm volatile("s_waitcnt vmcnt(0)" ::: "memory");
    __builtin_amdgcn_sched_barrier(0);

    const float* __restrict__ nb = noise + (size_t)b * C_;

    // Prologue: stage tile t=0 into buffer 0 (3 DMA loads, 3 outstanding).
    {
        const float* st = nb;
        GLOAD_LDS16(st + (size_t)i0 * 4, &nbuf[0][0 * 256 + wave * 64]);
        GLOAD_LDS16(st + (size_t)i1 * 4, &nbuf[0][1 * 256 + wave * 64]);
        GLOAD_LDS16(st + (size_t)i2 * 4, &nbuf[0][2 * 256 + wave * 64]);
    }

#pragma unroll
    for (int t = 0; t < T_; ++t) {
        const int cur = t & 1;
        if (t + 1 < T_) {
            const int nxt = cur ^ 1;
            const float* sn = nb + (size_t)(t + 1) * (size_t)(B_ * C_);
            GLOAD_LDS16(sn + (size_t)i0 * 4, &nbuf[nxt][0 * 256 + wave * 64]);
            GLOAD_LDS16(sn + (size_t)i1 * 4, &nbuf[nxt][1 * 256 + wave * 64]);
            GLOAD_LDS16(sn + (size_t)i2 * 4, &nbuf[nxt][2 * 256 + wave * 64]);
            // 6 outstanding; wait until only the 3 newest remain -> tile t ready.
            asm volatile("s_waitcnt vmcnt(3)" ::: "memory");
        } else {
            asm volatile("s_waitcnt vmcnt(0)" ::: "memory");
        }
        __builtin_amdgcn_sched_barrier(0);

        float4 nv0 = nbuf[cur][0 * 256 + tid];
        float4 nv1 = nbuf[cur][1 * 256 + tid];
        float4 nv2 = nbuf[cur][2 * 256 + tid];
        float n[12];
        n[0]=nv0.x; n[1]=nv0.y; n[2]=nv0.z; n[3]=nv0.w;
        n[4]=nv1.x; n[5]=nv1.y; n[6]=nv1.z; n[7]=nv1.w;
        n[8]=nv2.x; n[9]=nv2.y; n[10]=nv2.z; n[11]=nv2.w;
        float s_acc = 0.f, d_acc = 0.f;
#pragma unroll
        for (int j = 0; j < 12; ++j) {
            float x = fmaf(stdv, n[j], p[j]);   // tail lanes: -1e30 -> exp 0
            s_acc += __expf(x);
            d_acc  = fmaf(x, tr[j], d_acc);
        }
        S[t] = s_acc; D[t] = d_acc;
    }

    // 64-lane butterfly reduction of Tm and all 26 (S,D) pairs.
    for (int off = 32; off > 0; off >>= 1) {
        Tm += __shfl_xor(Tm, off);
#pragma unroll
        for (int t = 0; t <= T_; ++t) {
            S[t] += __shfl_xor(S[t], off);
            D[t] += __shfl_xor(D[t], off);
        }
    }

    // Cross-wave combine via LDS; threads 0..25 finish their t.
    __shared__ float redS[T_ + 1][4], redD[T_ + 1][4], redTm[4];
    const int lane = tid & 63;
    if (lane == 0) {
        redTm[wave] = Tm;
#pragma unroll
        for (int t = 0; t <= T_; ++t) { redS[t][wave] = S[t]; redD[t][wave] = D[t]; }
    }
    __syncthreads();
    if (tid <= T_) {
        float Sa  = redS[tid][0] + redS[tid][1] + redS[tid][2] + redS[tid][3];
        float Da  = redD[tid][0] + redD[tid][1] + redD[tid][2] + redD[tid][3];
        float Tma = redTm[0] + redTm[1] + redTm[2] + redTm[3];
        float lse = logf(Sa);                    // no max shift needed
        atomicAdd(&dsum[tid], (lse * Tma - Da) * 0.1f);
    }
}

// Single wave: depressor reduction over B=512, per-t means, elu, final 4 outputs.
__global__ __launch_bounds__(64) void ace_final(
    const float* __restrict__ logit_var,
    const float* __restrict__ dsum,
    float* __restrict__ out)
{
    const int lane = threadIdx.x;

    float dep = 0.0f;
    for (int i = lane; i < B_; i += 64)
        dep += __expf(logit_var[i]) - 1.0f;

    const float undist = dsum[T_] * (1.0f / B_);
    float d  = (lane < T_) ? dsum[lane] * (1.0f / B_) : 0.0f;
    float el = 0.0f;
    if (lane < T_) {
        float x   = undist - d;
        float elu = (x > 0.0f) ? x : (__expf(x) - 1.0f);
        el = -elu;
    }

    for (int off = 32; off > 0; off >>= 1) {
        dep += __shfl_xor(dep, off);
        d   += __shfl_xor(d, off);
        el  += __shfl_xor(el, off);
    }

    if (lane == 0) {
        out[0] = d  * (1.0f / T_);   // gce_loss
        out[1] = el * (1.0f / T_);   // variance_loss
        out[2] = undist;             // undistorted_loss
        out[3] = dep * (1.0f / B_);  // variance_depressor
    }
}

extern "C" void kernel_launch(void* const* d_in, const int* in_sizes, int n_in,
                              void* d_out, int out_size, void* d_ws, size_t ws_size,
                              hipStream_t stream) {
    const float* logit_var = (const float*)d_in[0];  // [512,1]
    const float* pred      = (const float*)d_in[1];  // [512,3000]
    const float* tru       = (const float*)d_in[2];  // [512,3000]
    const float* noise     = (const float*)d_in[3];  // [25,512,3000]
    float* out  = (float*)d_out;                     // 4 fp32 scalars
    float* dsum = (float*)d_ws;                      // (T+1) fp32 accumulators

    hipMemsetAsync(dsum, 0, (T_ + 1) * sizeof(float), stream);
    ace_rows<<<B_, 256, 0, stream>>>(logit_var, pred, tru, noise, dsum);
    ace_final<<<1, 64, 0, stream>>>(logit_var, dsum, out);
}